// Round 2
// baseline (100.827 us; speedup 1.0000x reference)
//
#include <hip/hip_runtime.h>

// TinyQuantumClassifier, collapsed form.
//
// The circuit after data encoding is a fixed linear map M (4x4, real):
//   M = C * (RY(t10) kron RY(t11)) * C * (RY(t00) kron RY(t01))
// and z0 = s^T (M^T D M) s with D = diag(1,1,-1,-1),
//   s = (cos(x1/2), sin(x1/2)) kron (cos(x2/2), sin(x2/2)).
// Degree-2 monomials in half-angle trig reduce to {1, cos x, sin x}, so
//   z0 = (1, cos x1, sin x1) . W . (1, cos x2, sin x2)^T
// with a uniform 3x3 W computed once per launch by a 1-thread setup kernel.
// Main kernel: 2 samples/thread -> 1 coalesced float4 load, 4 native trig,
// ~16 FMA, 1 coalesced float2 store. Memory-bound: 12 B/sample, ~16 us floor.

__global__ void tqc_setup(const float* __restrict__ theta, float* __restrict__ W) {
    // Single thread; precise trig (cost irrelevant, runs once per launch).
    float ang[4] = {theta[0], theta[1], theta[2], theta[3]};

    float M[4][4], K[4][4], T2[4][4];
    for (int i = 0; i < 4; ++i)
        for (int j = 0; j < 4; ++j) M[i][j] = (i == j) ? 1.f : 0.f;

    for (int l = 0; l < 2; ++l) {
        float ca = cosf(0.5f * ang[2 * l]),     sa = sinf(0.5f * ang[2 * l]);
        float cb = cosf(0.5f * ang[2 * l + 1]), sb = sinf(0.5f * ang[2 * l + 1]);
        float A[2][2]  = {{ca, -sa}, {sa, ca}};   // wire0 rotation
        float Bb[2][2] = {{cb, -sb}, {sb, cb}};   // wire1 rotation
        // K = A kron B, flat index (i,j) -> 2i+j (i = wire0)
        for (int i = 0; i < 2; ++i)
            for (int j = 0; j < 2; ++j)
                for (int k = 0; k < 2; ++k)
                    for (int m = 0; m < 2; ++m)
                        K[2 * i + j][2 * k + m] = A[i][k] * Bb[j][m];
        // T2 = K * M
        for (int i = 0; i < 4; ++i)
            for (int j = 0; j < 4; ++j) {
                float acc = 0.f;
                for (int k = 0; k < 4; ++k) acc += K[i][k] * M[k][j];
                T2[i][j] = acc;
            }
        // CNOT(0,1): swap flat components (1,0) <-> (1,1), i.e. rows 2,3
        for (int j = 0; j < 4; ++j) {
            M[0][j] = T2[0][j];
            M[1][j] = T2[1][j];
            M[2][j] = T2[3][j];
            M[3][j] = T2[2][j];
        }
    }

    // Q = M^T D M, D = diag(1,1,-1,-1)
    float Q[4][4];
    for (int r = 0; r < 4; ++r)
        for (int c = 0; c < 4; ++c) {
            float acc = 0.f;
            for (int t = 0; t < 4; ++t) {
                float d = (t < 2) ? 1.f : -1.f;
                acc += M[t][r] * d * M[t][c];
            }
            Q[r][c] = acc;
        }

    // Reduce p_a p_c (half-angle products) to basis {1, cos x, sin x}:
    // T[a][c] = coeff 3-vector
    const float T[2][2][3] = {{{0.5f, 0.5f, 0.f}, {0.f, 0.f, 0.5f}},
                              {{0.f, 0.f, 0.5f}, {0.5f, -0.5f, 0.f}}};
    for (int m = 0; m < 3; ++m)
        for (int n = 0; n < 3; ++n) {
            float acc = 0.f;
            for (int a = 0; a < 2; ++a)
                for (int b = 0; b < 2; ++b)
                    for (int c = 0; c < 2; ++c)
                        for (int d = 0; d < 2; ++d)
                            acc += Q[2 * a + b][2 * c + d] * T[a][c][m] * T[b][d][n];
            W[3 * m + n] = acc;
        }
}

__global__ __launch_bounds__(256) void tqc_main(
    const float4* __restrict__ feat4,  // feat4[t] = (x1,x2) for 2 samples
    const float*  __restrict__ W,      // 9 uniform coeffs (in d_ws)
    float2*       __restrict__ out2,   // 2 results per thread
    int n2)
{
    int t = blockIdx.x * blockDim.x + threadIdx.x;
    if (t >= n2) return;

    // Uniform coefficients -> scalar loads (address is SGPR + imm).
    float w0 = W[0], w1 = W[1], w2 = W[2];
    float w3 = W[3], w4 = W[4], w5 = W[5];
    float w6 = W[6], w7 = W[7], w8 = W[8];

    float4 f = feat4[t];

    float s1, c1, s2, c2;
    __sincosf(f.x, &s1, &c1);
    __sincosf(f.y, &s2, &c2);
    float r0 = (w0 + w1 * c2 + w2 * s2)
             + c1 * (w3 + w4 * c2 + w5 * s2)
             + s1 * (w6 + w7 * c2 + w8 * s2);

    __sincosf(f.z, &s1, &c1);
    __sincosf(f.w, &s2, &c2);
    float r1 = (w0 + w1 * c2 + w2 * s2)
             + c1 * (w3 + w4 * c2 + w5 * s2)
             + s1 * (w6 + w7 * c2 + w8 * s2);

    out2[t] = make_float2(r0, r1);
}

extern "C" void kernel_launch(void* const* d_in, const int* in_sizes, int n_in,
                              void* d_out, int out_size, void* d_ws, size_t ws_size,
                              hipStream_t stream) {
    const float* feat  = (const float*)d_in[0];  // [B,2] f32
    const float* theta = (const float*)d_in[1];  // [2,2] f32
    float* out = (float*)d_out;                  // [B,1] f32
    float* W   = (float*)d_ws;                   // 9 floats scratch

    int b  = in_sizes[0] / 2;  // samples
    int n2 = b / 2;            // threads (2 samples each); B = 8388608 is even

    tqc_setup<<<1, 1, 0, stream>>>(theta, W);

    int block = 256;
    int grid = (n2 + block - 1) / block;
    tqc_main<<<grid, block, 0, stream>>>(
        (const float4*)feat, W, (float2*)out, n2);
}